// Round 1
// 6653.230 us; speedup vs baseline: 8.2986x; 8.2986x over previous
//
#include <hip/hip_runtime.h>
#include <stdint.h>

// LSTMClassifier on MI355X — round 13: fix the broken flag poll.
// Round-12 evidence: k2_lstm = 267 ms, VALUBusy 0.34%, MfmaUtil 0.015%.
// 267ms/512 steps = 522 us/step == exactly the 4096-iteration bounded
// "fast" poll phase. The sc0 load NEVER observes the plain-store publish:
// on gfx950 the load scope encoding is (sc1,sc0) and agent scope needs
// sc1 — sc0 alone is NOT an L1 bypass, so the first poll caches a stale 0
// in L1 and every later poll hits it. The atomicAdd fallback (RMW at the
// coherence point) then succeeds instantly — hence correct-but-500x-slow.
//
// Fix: poll with __hip_atomic_load(ACQUIRE, AGENT) (emits sc1 + buffer_inv:
// true L1 bypass, and orders the subsequent h loads), publish with
// __hip_atomic_store(RELAXED, AGENT) after the vmcnt-draining barrier.
// Bounded RMW fallback kept purely as a hang-safety net (should never fire).
// Also: e-projection MFMAs (h-independent) now issue BEFORE the poll, so
// the flag round trip hides under real work.
//
// Workspace (50.6 MiB):
//   [0,4096)          int sync[]: [0]=leader, [8..16)=claim counters
//   [4096, +131.3KB)  int flags[513][64]     (memset 0 per launch)
//   [+, +33.6MB)      bf16 h_buf[513][64][512]  (h_buf[0] memset 0)
//   [+, +16.8MB)      bf16 e_seq[32768][256]

#define EMB   256
#define HID   512
#define NOUT  18
#define BATCH 64
#define SEQ   512
#define NPART 32     // scan workgroups = CUs on one XCD
#define WCOLS 16     // h-cols per wg (512/32)

typedef __attribute__((ext_vector_type(8))) short bf16x8;
typedef __attribute__((ext_vector_type(4))) float floatx4;

__device__ inline float bf2f(short u) {
    union { float f; uint32_t i; } v;
    v.i = ((uint32_t)(uint16_t)u) << 16;
    return v.f;
}
__device__ inline short f2bf(float f) {
    union { float f; uint32_t i; } v; v.f = f;
    uint32_t r = v.i + 0x7fffu + ((v.i >> 16) & 1u);   // RNE
    return (short)(r >> 16);
}
__device__ inline float sigm(float x) { return 1.f / (1.f + __expf(-x)); }
__device__ inline float tanh_fast(float x) {
    float xc = fminf(fmaxf(x, -15.f), 15.f);
    float e  = __expf(2.f * xc);
    return (e - 1.f) / (e + 1.f);
}

// Detect packed-bf16 vs fp32 float tensors (verified round 4 — keep).
__device__ inline bool detect_bf16(const void* emb_raw) {
    const uint32_t* w = (const uint32_t*)emb_raw;
    int votes = 0;
    #pragma unroll
    for (int i = 0; i < 8; i++) {
        uint32_t e = (w[i] >> 7) & 0xFFu;
        votes += (e >= 110u && e <= 135u) ? 1 : 0;
    }
    return votes >= 6;
}
__device__ inline float rd(const void* p, int idx, bool isbf) {
    return isbf ? bf2f(((const short*)p)[idx]) : ((const float*)p)[idx];
}

// load one 8-element bf16 fragment from a maybe-fp32 weight row
__device__ inline bf16x8 ldfrag(const void* base, size_t off, bool isbf) {
    if (isbf) return *(const bf16x8*)((const short*)base + off);
    const float* s = (const float*)base + off;
    bf16x8 v;
    #pragma unroll
    for (int j = 0; j < 8; j++) v[j] = f2bf(s[j]);
    return v;
}

// ---------------------------------------------------------------------------
// K0: e_seq[u][k] = emb[x[u&63][u>>6]][k] (bf16 out), u = s*64+b.
// ---------------------------------------------------------------------------
__global__ __launch_bounds__(256) void k0_gather(
    const int* __restrict__ x, const void* __restrict__ emb,
    short* __restrict__ eseq)
{
    const bool isbf = detect_bf16(emb);
    const int u0 = blockIdx.x * 32;
    #pragma unroll
    for (int it = 0; it < 4; it++) {
        int idx = it * 256 + threadIdx.x;          // 0..1023
        int u   = u0 + (idx >> 5);
        int ch  = (idx & 31) * 8;
        int tok = x[(u & 63) * SEQ + (u >> 6)];
        bf16x8 v;
        if (isbf) {
            v = *(const bf16x8*)((const short*)emb + (size_t)tok * EMB + ch);
        } else {
            const float* src = (const float*)emb + (size_t)tok * EMB + ch;
            #pragma unroll
            for (int j = 0; j < 8; j++) v[j] = f2bf(src[j]);
        }
        *(bf16x8*)(eseq + (size_t)u * EMB + ch) = v;
    }
}

// ---------------------------------------------------------------------------
// K2: intra-XCD persistent scan, register weights, agent-scope flag sync.
// 32 wgs; slot g owns h cols [16g,16g+16).
// ---------------------------------------------------------------------------
__global__ __launch_bounds__(256, 1) void k2_lstm(
    const void* __restrict__ w_hh, const void* __restrict__ w_ih,
    const void* __restrict__ b_ih, const void* __restrict__ b_hh,
    const void* __restrict__ emb, const short* __restrict__ eseq,
    short* __restrict__ hbuf, int* __restrict__ sync, int* __restrict__ flags)
{
    __shared__ float biasl[64];
    __shared__ int   sh_slot;

    const int t = threadIdx.x;

    // ---- XCD leader claim (round-9/10 verified; startup only).
    // Pigeonhole: 8*31 = 248 < 256 grid => some XCD always reaches NPART. ----
    if (t == 0) {
        unsigned xcd;
        asm volatile("s_getreg_b32 %0, hwreg(HW_REG_XCC_ID)" : "=s"(xcd));
        xcd &= 7u;
        int c = atomicAdd(&sync[8 + xcd], 1);
        if (c == NPART - 1) atomicCAS(&sync[0], 0, (int)xcd + 1);
        int L;
        while ((L = atomicAdd(&sync[0], 0)) == 0)
            __builtin_amdgcn_s_sleep(8);
        sh_slot = (L == (int)xcd + 1 && c < NPART) ? c : -1;
    }
    __syncthreads();
    const int g = sh_slot;
    if (g < 0) return;

    const bool isbf = detect_bf16(emb);
    const int lane = t & 63;
    const int w    = t >> 6;
    const int col  = lane & 15;
    const int quad = lane >> 4;

    // ---- B fragments to registers: breg[nt][kk], 96 x bf16x8 ----
    bf16x8 breg[4][24];
    #pragma unroll
    for (int nt = 0; nt < 4; nt++) {
        const size_t grow = (size_t)(nt * HID + g * WCOLS + col);
        #pragma unroll
        for (int kk = 0; kk < 16; kk++)
            breg[nt][kk] = ldfrag(w_hh, grow * HID + kk * 32 + quad * 8, isbf);
        #pragma unroll
        for (int kk = 0; kk < 8; kk++)
            breg[nt][16 + kk] = ldfrag(w_ih, grow * EMB + kk * 32 + quad * 8, isbf);
    }
    if (t < 64) {
        int grow = (t >> 4) * HID + g * WCOLS + (t & 15);
        biasl[t] = rd(b_ih, grow, isbf) + rd(b_hh, grow, isbf);
    }
    __syncthreads();
    const float bI = biasl[col],      bF = biasl[16 + col];
    const float bG = biasl[32 + col], bO = biasl[48 + col];

    float cre[4] = {0.f, 0.f, 0.f, 0.f};

    const short* eptr = eseq + (size_t)(w * 16 + col) * EMB + quad * 8;
    const short* hrd  = hbuf + (size_t)(w * 16 + col) * HID + quad * 8;
    short*       hwr  = hbuf + (size_t)(BATCH * HID)
                      + (size_t)(w * 16 + quad * 4) * HID + g * WCOLS + col;

    // ---- scan ----
    for (int step = 0; step < SEQ; step++) {
        // e A-frags + e-projection MFMAs: independent of the handshake —
        // run them BEFORE the poll so the flag round trip hides under MFMA.
        bf16x8 ae[8];
        #pragma unroll
        for (int kk = 0; kk < 8; kk++)
            ae[kk] = *(const bf16x8*)(eptr + kk * 32);

        floatx4 a0 = (floatx4){0.f,0.f,0.f,0.f}, a1 = a0, a2 = a0, a3 = a0;
        #pragma unroll
        for (int kk = 0; kk < 8; kk++) {
            a0 = __builtin_amdgcn_mfma_f32_16x16x32_bf16(ae[kk], breg[0][16+kk], a0, 0,0,0);
            a1 = __builtin_amdgcn_mfma_f32_16x16x32_bf16(ae[kk], breg[1][16+kk], a1, 0,0,0);
            a2 = __builtin_amdgcn_mfma_f32_16x16x32_bf16(ae[kk], breg[2][16+kk], a2, 0,0,0);
            a3 = __builtin_amdgcn_mfma_f32_16x16x32_bf16(ae[kk], breg[3][16+kk], a3, 0,0,0);
        }

        // wait: each wave's lanes 0..31 poll the 32 per-producer flags in
        // parallel with agent-scope ACQUIRE loads (sc1: true L1 bypass; the
        // acquire also fences the h loads below from being hoisted).
        // Bounded; RMW fallback guarantees progress even if scopes misbehave.
        if (step > 0 && lane < NPART) {
            int* fp = flags + (size_t)step * 64 + lane;
            int iters = 0;
            while (__hip_atomic_load(fp, __ATOMIC_ACQUIRE,
                                     __HIP_MEMORY_SCOPE_AGENT) == 0) {
                if (++iters > 8192) {
                    while (atomicAdd(fp, 0) == 0)
                        __builtin_amdgcn_s_sleep(8);
                    break;
                }
            }
        }

        // h window 1
        bf16x8 ah[8];
        #pragma unroll
        for (int kk = 0; kk < 8; kk++)
            ah[kk] = *(const bf16x8*)(hrd + kk * 32);
        #pragma unroll
        for (int kk = 0; kk < 8; kk++) {
            a0 = __builtin_amdgcn_mfma_f32_16x16x32_bf16(ah[kk], breg[0][kk], a0, 0,0,0);
            a1 = __builtin_amdgcn_mfma_f32_16x16x32_bf16(ah[kk], breg[1][kk], a1, 0,0,0);
            a2 = __builtin_amdgcn_mfma_f32_16x16x32_bf16(ah[kk], breg[2][kk], a2, 0,0,0);
            a3 = __builtin_amdgcn_mfma_f32_16x16x32_bf16(ah[kk], breg[3][kk], a3, 0,0,0);
        }
        // h window 2 (reuse ae registers)
        #pragma unroll
        for (int kk = 0; kk < 8; kk++)
            ae[kk] = *(const bf16x8*)(hrd + (8 + kk) * 32);
        #pragma unroll
        for (int kk = 0; kk < 8; kk++) {
            a0 = __builtin_amdgcn_mfma_f32_16x16x32_bf16(ae[kk], breg[0][8+kk], a0, 0,0,0);
            a1 = __builtin_amdgcn_mfma_f32_16x16x32_bf16(ae[kk], breg[1][8+kk], a1, 0,0,0);
            a2 = __builtin_amdgcn_mfma_f32_16x16x32_bf16(ae[kk], breg[2][8+kk], a2, 0,0,0);
            a3 = __builtin_amdgcn_mfma_f32_16x16x32_bf16(ae[kk], breg[3][8+kk], a3, 0,0,0);
        }

        // in-register epilogue
        #pragma unroll
        for (int r = 0; r < 4; r++) {
            float iv = sigm(a0[r] + bI);
            float fv = sigm(a1[r] + bF);
            float gv = tanh_fast(a2[r] + bG);
            float ov = sigm(a3[r] + bO);
            cre[r] = fv * cre[r] + iv * gv;
            float h = ov * tanh_fast(cre[r]);
            hwr[(size_t)r * HID] = f2bf(h);
        }
        __syncthreads();   // vmcnt-drain: all 256 threads' h-stores in L2
        if (t == 0)
            __hip_atomic_store(flags + (size_t)(step + 1) * 64 + g, 1,
                               __ATOMIC_RELAXED, __HIP_MEMORY_SCOPE_AGENT);

        eptr += (size_t)BATCH * EMB;
        hrd  += (size_t)BATCH * HID;
        hwr  += (size_t)BATCH * HID;
    }
}

// ---------------------------------------------------------------------------
// K3: logits = h_seq * W_fc^T + b_fc -> log_softmax(18). One token per thread.
// ---------------------------------------------------------------------------
__global__ __launch_bounds__(256) void k3_logits(
    const short* __restrict__ hbuf, const void* __restrict__ w_fc,
    const void* __restrict__ b_fc, const void* __restrict__ emb,
    void* __restrict__ out)
{
    __shared__ float Wf[NOUT][516];
    const bool isbf = detect_bf16(emb);
    const int t = threadIdx.x;
    for (int idx = t; idx < NOUT * 64; idx += 256) {
        int o = idx >> 6, ch = (idx & 63) * 8;
        #pragma unroll
        for (int j = 0; j < 8; j++)
            Wf[o][ch + j] = rd(w_fc, o * HID + ch + j, isbf);
    }
    __syncthreads();

    int u = blockIdx.x * 256 + t;              // u = s*64+b
    const short* hp = hbuf + (size_t)(u + BATCH) * HID;

    float acc[NOUT];
    #pragma unroll
    for (int o = 0; o < NOUT; o++) acc[o] = rd(b_fc, o, isbf);

    for (int ch = 0; ch < HID; ch += 8) {
        bf16x8 h8 = *(const bf16x8*)(hp + ch);
        float hf[8];
        #pragma unroll
        for (int j = 0; j < 8; j++) hf[j] = bf2f(h8[j]);
        #pragma unroll
        for (int o = 0; o < NOUT; o++) {
            floatx4 wa = *(const floatx4*)&Wf[o][ch];
            floatx4 wb = *(const floatx4*)&Wf[o][ch + 4];
            acc[o] += hf[0] * wa[0] + hf[1] * wa[1] + hf[2] * wa[2] + hf[3] * wa[3]
                    + hf[4] * wb[0] + hf[5] * wb[1] + hf[6] * wb[2] + hf[7] * wb[3];
        }
    }

    float mx = acc[0];
    #pragma unroll
    for (int o = 1; o < NOUT; o++) mx = fmaxf(mx, acc[o]);
    float s = 0.f;
    #pragma unroll
    for (int o = 0; o < NOUT; o++) s += __expf(acc[o] - mx);
    float lse = mx + __logf(s);

    int b = u & 63, sq = u >> 6;
    size_t base = (size_t)b * (SEQ * NOUT) + (size_t)sq * NOUT;
    if (isbf) {
        short* op = (short*)out + base;
        #pragma unroll
        for (int o = 0; o < NOUT; o++) op[o] = f2bf(acc[o] - lse);
    } else {
        float* op = (float*)out + base;
        #pragma unroll
        for (int o = 0; o < NOUT; o++) op[o] = acc[o] - lse;
    }
}

// ---------------------------------------------------------------------------
extern "C" void kernel_launch(void* const* d_in, const int* in_sizes, int n_in,
                              void* d_out, int out_size, void* d_ws, size_t ws_size,
                              hipStream_t stream) {
    const int*  x   = (const int*)d_in[0];
    const void* emb = d_in[1];
    const void* wih = d_in[2];
    const void* whh = d_in[3];
    const void* bih = d_in[4];
    const void* bhh = d_in[5];
    const void* wfc = d_in[6];
    const void* bfc = d_in[7];

    char*  ws    = (char*)d_ws;
    int*   sync  = (int*)ws;
    int*   flags = (int*)(ws + 4096);
    const size_t flagsz = (size_t)(SEQ + 1) * 64 * sizeof(int);   // 131.3 KB
    short* hbuf  = (short*)(ws + 4096 + ((flagsz + 255) & ~(size_t)255));
    short* eseq  = (short*)((char*)hbuf + (size_t)(SEQ + 1) * BATCH * HID * 2);

    (void)hipMemsetAsync(sync, 0, 4096, stream);                    // claim
    (void)hipMemsetAsync(flags, 0, flagsz, stream);                 // flags = 0
    (void)hipMemsetAsync(hbuf, 0, (size_t)BATCH * HID * 2, stream); // h_0 = 0

    k0_gather<<<1024, 256, 0, stream>>>(x, emb, eseq);
    k2_lstm<<<256, 256, 0, stream>>>(whh, wih, bih, bhh, emb, eseq,
                                     hbuf, sync, flags);
    k3_logits<<<128, 256, 0, stream>>>(hbuf, wfc, bfc, emb, d_out);
}